// Round 9
// baseline (668.873 us; speedup 1.0000x reference)
//
#include <hip/hip_runtime.h>

#define NN 50000
#define NE 800000

typedef __attribute__((ext_vector_type(8))) short bf16x8;
typedef __attribute__((ext_vector_type(4))) float f32x4;
typedef __attribute__((ext_vector_type(2))) float f32x2;

__device__ __forceinline__ unsigned short f2bf(float f) {
    union { float f; unsigned u; } v; v.f = f;
    unsigned r = v.u + 0x7FFFu + ((v.u >> 16) & 1u);
    return (unsigned short)(r >> 16);
}

// 32-bit-offset gathers (uniform 64-bit base + 32-bit voffset)
__device__ __forceinline__ int4 ld_ep(const int4* ep, unsigned idx) {
    return *(const int4*)((const char*)ep + (size_t)(idx * 16u));
}
__device__ __forceinline__ float ld_x(const float* X, unsigned byteoff) {
    return *(const float*)((const char*)X + (size_t)byteoff);
}

// bf16 LDS A-fragment layout (16 nodes/block):
//   element (kstep kk, r = k&31, node m) at ushort index
//   kk*544 + (r>>3)*136 + m*8 + (r&7)
__device__ __forceinline__ int us_idx(int kk, int r, int m) {
    return kk*544 + (r >> 3)*136 + m*8 + (r & 7);
}

// dense hat-basis accumulate (for divergent-edge kernels): v = f + t reconstructed.
template<bool HS>
__device__ __forceinline__ void edge_acc(float* h, float& hs, const int4& p, float x) {
    f32x2 vp = {(float)(p.y & 3) + __int_as_float(p.z),
                (float)(p.y >> 2) + __int_as_float(p.w)};
    const f32x2 zero = {0.f, 0.f};
    f32x2 wxy[5];
#pragma unroll
    for (int r = 0; r < 5; ++r) {
        f32x2 wr = 1.f - __builtin_elementwise_abs(vp - (float)r);
        wxy[r] = __builtin_elementwise_max(wr, zero);
    }
    if (HS) hs += x;
#pragma unroll
    for (int r1 = 0; r1 < 5; ++r1) {
        float ty = x * wxy[r1].y;
#pragma unroll
        for (int r0 = 0; r0 < 5; ++r0)
            h[r1*5 + r0] = fmaf(wxy[r0].x, ty, h[r1*5 + r0]);
    }
}

// sparse 4-corner accumulate, wave-uniform edge: scalarized 16-way switch.
__device__ __forceinline__ void edge_acc_sw(float* h, const int4& p, float x) {
    const int fib = __builtin_amdgcn_readfirstlane(p.y);   // f0 + 4*f1, wave-uniform
    const float t0 = __int_as_float(p.z);
    const float t1 = __int_as_float(p.w);
    const float s1 = t1 * x;
    const float s0 = x - s1;          // (1-t1)*x
    const float b  = t0 * s0, a = s0 - b;   // a=(1-t0)(1-t1)x  b=t0(1-t1)x
    const float d  = t0 * s1, c = s1 - d;   // c=(1-t0)t1 x     d=t0 t1 x
#define CORNER_CASE(F0,F1) \
    case (F0 + 4*(F1)): \
        h[(F0) + 5*(F1)]     += a;  h[(F0) + 5*(F1) + 1] += b; \
        h[(F0) + 5*(F1) + 5] += c;  h[(F0) + 5*(F1) + 6] += d; \
        break;
    switch (fib) {
        CORNER_CASE(0,0) CORNER_CASE(1,0) CORNER_CASE(2,0) CORNER_CASE(3,0)
        CORNER_CASE(0,1) CORNER_CASE(1,1) CORNER_CASE(2,1) CORNER_CASE(3,1)
        CORNER_CASE(0,2) CORNER_CASE(1,2) CORNER_CASE(2,2) CORNER_CASE(3,2)
        CORNER_CASE(0,3) CORNER_CASE(1,3) CORNER_CASE(2,3) CORNER_CASE(3,3)
    }
#undef CORNER_CASE
}

// ---------------- setup kernels ----------------
__global__ __launch_bounds__(256) void k_zero(int* degi, int* cur, float* stats) {
    int i = blockIdx.x*256 + threadIdx.x;
    int stride = gridDim.x*256;
    for (int j = i; j < NN; j += stride) { degi[j] = 0; cur[j] = 0; }
    if (i < 384) stats[i] = 0.f;
}

__global__ __launch_bounds__(256) void k_hist(const int* __restrict__ dst, int* degi) {
    int e = blockIdx.x*256 + threadIdx.x;
    if (e < NE) atomicAdd(&degi[dst[e]], 1);
}

__global__ __launch_bounds__(256) void k_scan_block(const int* __restrict__ degi,
                                                    int* off, int* bsum) {
    __shared__ int sh[256];
    int t = threadIdx.x;
    int base = blockIdx.x * 1024;
    int v[4]; int s = 0;
#pragma unroll
    for (int j = 0; j < 4; j++) {
        int idx = base + t*4 + j;
        v[j] = (idx < NN) ? degi[idx] : 0;
        s += v[j];
    }
    sh[t] = s; __syncthreads();
    for (int ofs = 1; ofs < 256; ofs <<= 1) {
        int x = (t >= ofs) ? sh[t - ofs] : 0;
        __syncthreads();
        sh[t] += x;
        __syncthreads();
    }
    int ex = sh[t] - s;
#pragma unroll
    for (int j = 0; j < 4; j++) {
        int idx = base + t*4 + j;
        if (idx < NN) off[idx] = ex;
        ex += v[j];
    }
    if (t == 255) bsum[blockIdx.x] = sh[255];
}

__global__ __launch_bounds__(256) void k_scan_top(const int* __restrict__ bsum,
                                                  int* bpre, int nb) {
    __shared__ int sh[256];
    int t = threadIdx.x;
    int s = (t < nb) ? bsum[t] : 0;
    sh[t] = s; __syncthreads();
    for (int ofs = 1; ofs < 256; ofs <<= 1) {
        int x = (t >= ofs) ? sh[t - ofs] : 0;
        __syncthreads();
        sh[t] += x;
        __syncthreads();
    }
    if (t < nb) bpre[t] = sh[t] - s;
}

__global__ __launch_bounds__(256) void k_scan_add(int* off, const int* __restrict__ bpre) {
    int i = blockIdx.x*256 + threadIdx.x;
    if (i < NN) off[i] += bpre[i >> 10];
    if (i == 0) off[NN] = NE;
}

// ep = (src, f0+4*f1, t0, t1): exact reference floor/frac corner form.
__global__ __launch_bounds__(256) void k_scatter(const int* __restrict__ src,
                                                 const int* __restrict__ dst,
                                                 const float* __restrict__ ea,
                                                 const int* __restrict__ off, int* cur,
                                                 int4* __restrict__ ep) {
    int e = blockIdx.x*256 + threadIdx.x;
    if (e >= NE) return;
    int d = dst[e];
    int p = off[d] + atomicAdd(&cur[d], 1);
    float v0 = ea[2*e]     * 4.f;
    float v1 = ea[2*e + 1] * 4.f;
    float f0 = fminf(fmaxf(floorf(v0), 0.f), 3.f);
    float f1 = fminf(fmaxf(floorf(v1), 0.f), 3.f);
    ep[p] = make_int4(src[e], (int)f0 + 4*(int)f1,
                      __float_as_int(v0 - f0), __float_as_int(v1 - f1));
}

// Pre-tile [W ; root] (f32, row-major [K,64]) into MFMA-B bf16 layout:
// Wb[((kk*4+cot)*64+lane)*8 + j] = src[k = kk*32+(lane>>4)*8+j][co = 16*cot+(lane&15)]
__global__ __launch_bounds__(256) void k_wprep(const float* __restrict__ W,
                                               const float* __restrict__ root,
                                               int KTC, unsigned short* Wb) {
    int tid = blockIdx.x*256 + threadIdx.x;
    int lane = tid & 63, cot = (tid >> 6) & 3, kk = tid >> 8;
    int co = 16*cot + (lane & 15);
    int kbase = kk*32 + ((lane >> 4) * 8);
    union { unsigned short s[8]; uint4 v; } u;
#pragma unroll
    for (int j = 0; j < 8; j++) {
        int k = kbase + j;
        float val = (k < KTC) ? W[(size_t)k*64 + co] : root[(size_t)(k - KTC)*64 + co];
        u.s[j] = f2bf(val);
    }
    *(uint4*)(Wb + (size_t)tid * 8) = u.v;
}

// ---------------- conv1 + convS fused: 16 nodes/block, bf16 LDS fragments ----
// 512 threads, 8 waves. Half-wave (t>>5) owns node g; ci = t&31. Dense hat
// (edges diverge across halves). Phase B: waves 0-3 agg1; waves 4-7 aggS.
__global__ __launch_bounds__(512, 4) void k_conv1s(
        const float* __restrict__ X,
        const int* __restrict__ off,
        const int4* __restrict__ ep,
        const unsigned short* __restrict__ Wb1,
        const unsigned short* __restrict__ WbS,
        const float* __restrict__ b1,
        const float* __restrict__ bs,
        float* __restrict__ agg1,
        float* __restrict__ aggS) {
    __shared__ __align__(16) unsigned short hb[28*544];  // 30.5 KB
    const int t = threadIdx.x;
    const int g = t >> 5;          // node slot 0..15
    const int ci = t & 31;
    const int n0 = blockIdx.x * 16;
    const int n = n0 + g;

    float h[25], hs = 0.f;
#pragma unroll
    for (int i = 0; i < 25; ++i) h[i] = 0.f;

    const int ebeg = off[n], eend = off[n + 1];
    const int last = eend - 1;
    const float rdeg = 1.f / (float)max(eend - ebeg, 1);

    for (int i = ebeg; i < eend; i += 4) {
        int4 p[4]; float xv[4];
#pragma unroll
        for (int u = 0; u < 4; ++u) p[u] = ld_ep(ep, (unsigned)min(i + u, last));
#pragma unroll
        for (int u = 0; u < 4; ++u) {
            xv[u] = ld_x(X, (unsigned)p[u].x * 128u + (unsigned)ci * 4u);
            if (i + u >= eend) xv[u] = 0.f;
        }
#pragma unroll
        for (int u = 0; u < 4; ++u) edge_acc<true>(h, hs, p[u], xv[u]);
    }

    // ---- dump bf16 fragments: kstep = wi; 25 = x; 26 = hs; 27 = x ----
    const int bw = us_idx(0, ci, g);
    const unsigned short xbf = f2bf(X[(size_t)n*32 + ci]);
#pragma unroll
    for (int wi = 0; wi < 25; ++wi) hb[wi*544 + bw] = f2bf(h[wi] * rdeg);
    hb[25*544 + bw] = xbf;
    hb[26*544 + bw] = f2bf(hs * rdeg);
    hb[27*544 + bw] = xbf;
    __syncthreads();

    // ---- phase B ----
    const int lane = t & 63, w = t >> 6;
    const int m = lane & 15, qq = lane >> 4;
    const int co = (w & 3)*16 + m;
    if (w < 4) {
        f32x4 acc = {0.f, 0.f, 0.f, 0.f};
        for (int kk = 0; kk < 26; ++kk) {
            bf16x8 av = *(const bf16x8*)&hb[kk*544 + qq*136 + m*8];
            bf16x8 bv = *(const bf16x8*)(Wb1 + (size_t)((kk*4 + w)*64 + lane) * 8);
            acc = __builtin_amdgcn_mfma_f32_16x16x32_bf16(av, bv, acc, 0, 0, 0);
        }
        const float bb = b1[co];
#pragma unroll
        for (int r = 0; r < 4; ++r)
            agg1[(size_t)(n0 + qq*4 + r)*64 + co] = acc[r] + bb;
    } else {
        f32x4 accs = {0.f, 0.f, 0.f, 0.f};
#pragma unroll
        for (int s = 0; s < 2; ++s) {
            bf16x8 av = *(const bf16x8*)&hb[(26 + s)*544 + qq*136 + m*8];
            bf16x8 bv = *(const bf16x8*)(WbS + (size_t)((s*4 + (w & 3))*64 + lane) * 8);
            accs = __builtin_amdgcn_mfma_f32_16x16x32_bf16(av, bv, accs, 0, 0, 0);
        }
        const float bb = bs[co];
#pragma unroll
        for (int r = 0; r < 4; ++r)
            aggS[(size_t)(n0 + qq*4 + r)*64 + co] = accs[r] + bb;
    }
}

// ---------------- conv2: 16 nodes/block, scalarized 4-corner edge loop ----
// 512 threads, 8 waves. Wave w owns nodes 2w, 2w+1 (edge wave-uniform -> switch).
__global__ __launch_bounds__(512, 4) void k_conv2(
        const float* __restrict__ X,
        const int* __restrict__ off,
        const int4* __restrict__ ep,
        const unsigned short* __restrict__ Wb2,
        const float* __restrict__ b2,
        float* __restrict__ agg) {
    __shared__ __align__(16) unsigned short hb[52*544];  // 56.6 KB
    const int t = threadIdx.x, lane = t & 63, w = t >> 6;
    const int n0 = blockIdx.x * 16;
    const int kh = lane >> 5, r = lane & 31;   // k = wi*64 + lane -> kstep wi*2+kh

#pragma unroll
    for (int nn = 0; nn < 2; ++nn) {
        const int g = 2*w + nn;
        const int n = n0 + g;
        float h[25];
#pragma unroll
        for (int i = 0; i < 25; ++i) h[i] = 0.f;

        const int ebeg = off[n], eend = off[n + 1];
        const int last = eend - 1;
        const float rdeg = 1.f / (float)max(eend - ebeg, 1);

        for (int i = ebeg; i < eend; i += 4) {
            int4 p[4]; float xv[4];
#pragma unroll
            for (int u = 0; u < 4; ++u) p[u] = ld_ep(ep, (unsigned)min(i + u, last));
#pragma unroll
            for (int u = 0; u < 4; ++u) {
                xv[u] = ld_x(X, (unsigned)p[u].x * 256u + (unsigned)lane * 4u);
                if (i + u >= eend) xv[u] = 0.f;
            }
#pragma unroll
            for (int u = 0; u < 4; ++u) edge_acc_sw(h, p[u], xv[u]);
        }

        // dump: wi 0..24 -> ksteps wi*2+kh; x -> ksteps 50,51
        const int bw = us_idx(0, r, g);
#pragma unroll
        for (int wi = 0; wi < 25; ++wi)
            hb[(wi*2 + kh)*544 + bw] = f2bf(h[wi] * rdeg);
        hb[(50 + kh)*544 + bw] = f2bf(X[(size_t)n*64 + lane]);
    }
    __syncthreads();

    if (w >= 4) return;

    const int m = lane & 15, qq = lane >> 4;
    f32x4 acc = {0.f, 0.f, 0.f, 0.f};
    for (int kk = 0; kk < 52; ++kk) {
        bf16x8 av = *(const bf16x8*)&hb[kk*544 + qq*136 + m*8];
        bf16x8 bv = *(const bf16x8*)(Wb2 + (size_t)((kk*4 + w)*64 + lane) * 8);
        acc = __builtin_amdgcn_mfma_f32_16x16x32_bf16(av, bv, acc, 0, 0, 0);
    }
    const int co = w*16 + m;
    const float bb = b2[co];
#pragma unroll
    for (int rr = 0; rr < 4; ++rr)
        agg[(size_t)(n0 + qq*4 + rr)*64 + co] = acc[rr] + bb;
}

// ---------------- batch norm ----------------
__global__ __launch_bounds__(256) void k_bnstats(const float* __restrict__ agg, float* stats) {
    __shared__ float sh0[256], sh1[256];
    int t = threadIdx.x;
    float s = 0.f, ss = 0.f;
    int stride = gridDim.x * 256;
    for (int i = blockIdx.x*256 + t; i < NN*64; i += stride) {
        float v = agg[i];
        s += v; ss += v*v;
    }
    sh0[t] = s; sh1[t] = ss;
    __syncthreads();
    if (t < 64) {
        float a = sh0[t] + sh0[t+64] + sh0[t+128] + sh0[t+192];
        float b = sh1[t] + sh1[t+64] + sh1[t+128] + sh1[t+192];
        atomicAdd(&stats[t], a);
        atomicAdd(&stats[64 + t], b);
    }
}

__device__ __forceinline__ float eluf(float u) { return u > 0.f ? u : expm1f(u); }

__global__ __launch_bounds__(256) void k_bn_elu(const float* __restrict__ agg,
                                                const float* __restrict__ stats,
                                                const float* __restrict__ gamma,
                                                const float* __restrict__ beta,
                                                float* __restrict__ out) {
    int i = blockIdx.x*256 + threadIdx.x;
    if (i >= NN*16) return;
    float4 v = ((const float4*)agg)[i];
    float r[4] = {v.x, v.y, v.z, v.w};
    int c0 = (i << 2) & 63;
#pragma unroll
    for (int j = 0; j < 4; j++) {
        int c = c0 + j;
        float mu = stats[c] * (1.f/NN);
        float var = stats[64 + c] * (1.f/NN) - mu*mu;
        float sc = gamma[c] * rsqrtf(fmaxf(var, 0.f) + 1e-5f);
        r[j] = eluf((r[j] - mu)*sc + beta[c]);
    }
    ((float4*)out)[i] = make_float4(r[0], r[1], r[2], r[3]);
}

__global__ __launch_bounds__(256) void k_bn_final(const float* __restrict__ a2,
                                                  const float* __restrict__ st2,
                                                  const float* __restrict__ g2,
                                                  const float* __restrict__ be2,
                                                  const float* __restrict__ as,
                                                  const float* __restrict__ sts,
                                                  const float* __restrict__ gs,
                                                  const float* __restrict__ bes,
                                                  float* __restrict__ out) {
    int i = blockIdx.x*256 + threadIdx.x;
    if (i >= NN*16) return;
    float4 v2 = ((const float4*)a2)[i];
    float4 vs = ((const float4*)as)[i];
    float r2v[4] = {v2.x, v2.y, v2.z, v2.w};
    float rsv[4] = {vs.x, vs.y, vs.z, vs.w};
    float o[4];
    int c0 = (i << 2) & 63;
#pragma unroll
    for (int j = 0; j < 4; j++) {
        int c = c0 + j;
        float mu2 = st2[c] * (1.f/NN);
        float var2 = st2[64 + c] * (1.f/NN) - mu2*mu2;
        float sc2 = g2[c] * rsqrtf(fmaxf(var2, 0.f) + 1e-5f);
        float mus = sts[c] * (1.f/NN);
        float vars = sts[64 + c] * (1.f/NN) - mus*mus;
        float scs = gs[c] * rsqrtf(fmaxf(vars, 0.f) + 1e-5f);
        float u = (r2v[j] - mu2)*sc2 + be2[c] + (rsv[j] - mus)*scs + bes[c];
        o[j] = eluf(u);
    }
    ((float4*)out)[i] = make_float4(o[0], o[1], o[2], o[3]);
}

extern "C" void kernel_launch(void* const* d_in, const int* in_sizes, int n_in,
                              void* d_out, int out_size, void* d_ws, size_t ws_size,
                              hipStream_t stream) {
    const float* x   = (const float*)d_in[0];
    const int*   ei  = (const int*)d_in[1];
    const float* ea  = (const float*)d_in[2];
    const float* w1  = (const float*)d_in[3];
    const float* r1  = (const float*)d_in[4];
    const float* b1  = (const float*)d_in[5];
    const float* g1  = (const float*)d_in[6];
    const float* be1 = (const float*)d_in[7];
    const float* w2  = (const float*)d_in[8];
    const float* r2  = (const float*)d_in[9];
    const float* b2  = (const float*)d_in[10];
    const float* g2  = (const float*)d_in[11];
    const float* be2 = (const float*)d_in[12];
    const float* wsN = (const float*)d_in[13];
    const float* rs  = (const float*)d_in[14];
    const float* bs  = (const float*)d_in[15];
    const float* gs  = (const float*)d_in[16];
    const float* bes = (const float*)d_in[17];
    const int* srcp = ei;
    const int* dstp = ei + NE;

    char* wsb = (char*)d_ws;
    size_t o = 0;
    auto alloc = [&](size_t bytes) -> char* {
        char* p = wsb + o;
        o += (bytes + 255) & ~(size_t)255;
        return p;
    };
    int*    degi    = (int*)   alloc((size_t)NN * 4);
    int*    cur     = (int*)   alloc((size_t)NN * 4);
    int*    off     = (int*)   alloc((size_t)(NN + 1) * 4);
    int*    bsum    = (int*)   alloc(256 * 4);
    int*    bpre    = (int*)   alloc(256 * 4);
    int4*   ep      = (int4*)  alloc((size_t)NE * 16);
    unsigned short* Wb1 = (unsigned short*)alloc(26 * 4096);
    unsigned short* WbS = (unsigned short*)alloc(2 * 4096);
    unsigned short* Wb2 = (unsigned short*)alloc(52 * 4096);
    float*  agg1    = (float*) alloc((size_t)NN * 64 * 4);  // reused for conv2 output
    float*  aggS    = (float*) alloc((size_t)NN * 64 * 4);
    float*  h1      = (float*) alloc((size_t)NN * 64 * 4);
    float*  stats   = (float*) alloc(384 * 4);
    (void)ws_size; (void)in_sizes; (void)n_in; (void)out_size;

    float* out = (float*)d_out;

    k_zero<<<196, 256, 0, stream>>>(degi, cur, stats);
    k_hist<<<3125, 256, 0, stream>>>(dstp, degi);
    k_scan_block<<<49, 256, 0, stream>>>(degi, off, bsum);
    k_scan_top<<<1, 256, 0, stream>>>(bsum, bpre, 49);
    k_scan_add<<<196, 256, 0, stream>>>(off, bpre);
    k_scatter<<<3125, 256, 0, stream>>>(srcp, dstp, ea, off, cur, ep);

    k_wprep<<<26, 256, 0, stream>>>(w1, r1, 800, Wb1);
    k_wprep<<<2, 256, 0, stream>>>(wsN, rs, 32, WbS);
    k_wprep<<<52, 256, 0, stream>>>(w2, r2, 1600, Wb2);

    k_conv1s<<<3125, 512, 0, stream>>>(x, off, ep, Wb1, WbS, b1, bs, agg1, aggS);
    k_bnstats<<<256, 256, 0, stream>>>(agg1, stats);
    k_bn_elu<<<3125, 256, 0, stream>>>(agg1, stats, g1, be1, h1);

    k_conv2<<<3125, 512, 0, stream>>>(h1, off, ep, Wb2, b2, agg1);
    k_bnstats<<<256, 256, 0, stream>>>(agg1, stats + 128);
    k_bnstats<<<256, 256, 0, stream>>>(aggS, stats + 256);
    k_bn_final<<<3125, 256, 0, stream>>>(agg1, stats + 128, g2, be2,
                                         aggS, stats + 256, gs, bes, out);
}

// Round 10
// 489.859 us; speedup vs baseline: 1.3654x; 1.3654x over previous
//
#include <hip/hip_runtime.h>

#define NN 50000
#define NE 800000

typedef __attribute__((ext_vector_type(8))) short bf16x8;
typedef __attribute__((ext_vector_type(4))) float f32x4;
typedef __attribute__((ext_vector_type(2))) float f32x2;

__device__ __forceinline__ unsigned short f2bf(float f) {
    union { float f; unsigned u; } v; v.f = f;
    unsigned r = v.u + 0x7FFFu + ((v.u >> 16) & 1u);
    return (unsigned short)(r >> 16);
}

// 32-bit-offset gathers (uniform 64-bit base + 32-bit voffset)
__device__ __forceinline__ int4 ld_ep(const int4* ep, unsigned idx) {
    return *(const int4*)((const char*)ep + (size_t)(idx * 16u));
}
__device__ __forceinline__ float ld_x(const float* X, unsigned byteoff) {
    return *(const float*)((const char*)X + (size_t)byteoff);
}

// bf16 LDS A-fragment layout (16 nodes/block):
//   element (kstep kk, r = k&31, node m) at ushort index
//   kk*544 + (r>>3)*136 + m*8 + (r&7)
__device__ __forceinline__ int us_idx(int kk, int r, int m) {
    return kk*544 + (r >> 3)*136 + m*8 + (r & 7);
}

// dense hat-basis accumulate (one edge; v0,v1 raw): h[25] += x*wx*wy, hs += x.
template<bool HS>
__device__ __forceinline__ void edge_acc(float* h, float& hs, const int4& p, float x) {
    const f32x2 zero = {0.f, 0.f};
    f32x2 vp = {__int_as_float(p.z), __int_as_float(p.w)};
    f32x2 wxy[5];
#pragma unroll
    for (int r = 0; r < 5; ++r) {
        f32x2 wr = 1.f - __builtin_elementwise_abs(vp - (float)r);
        wxy[r] = __builtin_elementwise_max(wr, zero);
    }
    if (HS) hs += x;
#pragma unroll
    for (int r1 = 0; r1 < 5; ++r1) {
        float ty = x * wxy[r1].y;
#pragma unroll
        for (int r0 = 0; r0 < 5; ++r0)
            h[r1*5 + r0] = fmaf(wxy[r0].x, ty, h[r1*5 + r0]);
    }
}

// dense hat-basis accumulate for a PAIR of edges (node A in .x, node B in .y):
// straight-line, compile-time indices -> no scratch-demotion risk.
__device__ __forceinline__ void edge_acc_pair(f32x2* h2, const int4& pA, const int4& pB,
                                              float xA, float xB) {
    const f32x2 zero = {0.f, 0.f};
    f32x2 vp0 = {__int_as_float(pA.z), __int_as_float(pB.z)};
    f32x2 vp1 = {__int_as_float(pA.w), __int_as_float(pB.w)};
    f32x2 xp  = {xA, xB};
    f32x2 wx[5], wy[5];
#pragma unroll
    for (int r = 0; r < 5; ++r) {
        f32x2 w0 = 1.f - __builtin_elementwise_abs(vp0 - (float)r);
        f32x2 w1 = 1.f - __builtin_elementwise_abs(vp1 - (float)r);
        wx[r] = __builtin_elementwise_max(w0, zero);
        wy[r] = __builtin_elementwise_max(w1, zero);
    }
#pragma unroll
    for (int r1 = 0; r1 < 5; ++r1) {
        f32x2 ty = xp * wy[r1];
#pragma unroll
        for (int r0 = 0; r0 < 5; ++r0)
            h2[r1*5 + r0] = __builtin_elementwise_fma(wx[r0], ty, h2[r1*5 + r0]);
    }
}

// ---------------- setup kernels ----------------
__global__ __launch_bounds__(256) void k_zero(int* degi, int* cur, float* stats) {
    int i = blockIdx.x*256 + threadIdx.x;
    int stride = gridDim.x*256;
    for (int j = i; j < NN; j += stride) { degi[j] = 0; cur[j] = 0; }
    if (i < 384) stats[i] = 0.f;
}

__global__ __launch_bounds__(256) void k_hist(const int* __restrict__ dst, int* degi) {
    int e = blockIdx.x*256 + threadIdx.x;
    if (e < NE) atomicAdd(&degi[dst[e]], 1);
}

__global__ __launch_bounds__(256) void k_scan_block(const int* __restrict__ degi,
                                                    int* off, int* bsum) {
    __shared__ int sh[256];
    int t = threadIdx.x;
    int base = blockIdx.x * 1024;
    int v[4]; int s = 0;
#pragma unroll
    for (int j = 0; j < 4; j++) {
        int idx = base + t*4 + j;
        v[j] = (idx < NN) ? degi[idx] : 0;
        s += v[j];
    }
    sh[t] = s; __syncthreads();
    for (int ofs = 1; ofs < 256; ofs <<= 1) {
        int x = (t >= ofs) ? sh[t - ofs] : 0;
        __syncthreads();
        sh[t] += x;
        __syncthreads();
    }
    int ex = sh[t] - s;
#pragma unroll
    for (int j = 0; j < 4; j++) {
        int idx = base + t*4 + j;
        if (idx < NN) off[idx] = ex;
        ex += v[j];
    }
    if (t == 255) bsum[blockIdx.x] = sh[255];
}

__global__ __launch_bounds__(256) void k_scan_top(const int* __restrict__ bsum,
                                                  int* bpre, int nb) {
    __shared__ int sh[256];
    int t = threadIdx.x;
    int s = (t < nb) ? bsum[t] : 0;
    sh[t] = s; __syncthreads();
    for (int ofs = 1; ofs < 256; ofs <<= 1) {
        int x = (t >= ofs) ? sh[t - ofs] : 0;
        __syncthreads();
        sh[t] += x;
        __syncthreads();
    }
    if (t < nb) bpre[t] = sh[t] - s;
}

__global__ __launch_bounds__(256) void k_scan_add(int* off, const int* __restrict__ bpre) {
    int i = blockIdx.x*256 + threadIdx.x;
    if (i < NN) off[i] += bpre[i >> 10];
    if (i == 0) off[NN] = NE;
}

// ep = (src, 0, v0, v1) with v = pseudo*4 in [0,4); hat weights derive from v.
__global__ __launch_bounds__(256) void k_scatter(const int* __restrict__ src,
                                                 const int* __restrict__ dst,
                                                 const float* __restrict__ ea,
                                                 const int* __restrict__ off, int* cur,
                                                 int4* __restrict__ ep) {
    int e = blockIdx.x*256 + threadIdx.x;
    if (e >= NE) return;
    int d = dst[e];
    int p = off[d] + atomicAdd(&cur[d], 1);
    float v0 = ea[2*e]     * 4.f;
    float v1 = ea[2*e + 1] * 4.f;
    ep[p] = make_int4(src[e], 0, __float_as_int(v0), __float_as_int(v1));
}

// Pre-tile [W ; root] (f32, row-major [K,64]) into MFMA-B bf16 layout:
// Wb[((kk*4+cot)*64+lane)*8 + j] = src[k = kk*32+(lane>>4)*8+j][co = 16*cot+(lane&15)]
__global__ __launch_bounds__(256) void k_wprep(const float* __restrict__ W,
                                               const float* __restrict__ root,
                                               int KTC, unsigned short* Wb) {
    int tid = blockIdx.x*256 + threadIdx.x;
    int lane = tid & 63, cot = (tid >> 6) & 3, kk = tid >> 8;
    int co = 16*cot + (lane & 15);
    int kbase = kk*32 + ((lane >> 4) * 8);
    union { unsigned short s[8]; uint4 v; } u;
#pragma unroll
    for (int j = 0; j < 8; j++) {
        int k = kbase + j;
        float val = (k < KTC) ? W[(size_t)k*64 + co] : root[(size_t)(k - KTC)*64 + co];
        u.s[j] = f2bf(val);
    }
    *(uint4*)(Wb + (size_t)tid * 8) = u.v;
}

// ---------------- conv1 + convS fused: 16 nodes/block, bf16 LDS fragments ----
// 512 threads, 8 waves. Half-wave (t>>5) owns node g; ci = t&31.
// Phase B: waves 0-3 -> agg1 co-tile w (26 ksteps); waves 4-7 -> aggS (2 ksteps).
__global__ __launch_bounds__(512, 4) void k_conv1s(
        const float* __restrict__ X,
        const int* __restrict__ off,
        const int4* __restrict__ ep,
        const unsigned short* __restrict__ Wb1,
        const unsigned short* __restrict__ WbS,
        const float* __restrict__ b1,
        const float* __restrict__ bs,
        float* __restrict__ agg1,
        float* __restrict__ aggS) {
    __shared__ __align__(16) unsigned short hb[28*544];  // 30.5 KB
    const int t = threadIdx.x;
    const int g = t >> 5;          // node slot 0..15
    const int ci = t & 31;
    const int n0 = blockIdx.x * 16;
    const int n = n0 + g;

    float h[25], hs = 0.f;
#pragma unroll
    for (int i = 0; i < 25; ++i) h[i] = 0.f;

    const int ebeg = off[n], eend = off[n + 1];
    const int last = eend - 1;
    const float rdeg = 1.f / (float)max(eend - ebeg, 1);

    for (int i = ebeg; i < eend; i += 4) {
        int4 p[4]; float xv[4];
#pragma unroll
        for (int u = 0; u < 4; ++u) p[u] = ld_ep(ep, (unsigned)min(i + u, last));
#pragma unroll
        for (int u = 0; u < 4; ++u) {
            xv[u] = ld_x(X, (unsigned)p[u].x * 128u + (unsigned)ci * 4u);
            if (i + u >= eend) xv[u] = 0.f;
        }
#pragma unroll
        for (int u = 0; u < 4; ++u) edge_acc<true>(h, hs, p[u], xv[u]);
    }

    // ---- dump bf16 fragments: kstep = wi; 25 = x; 26 = hs; 27 = x ----
    const int bw = us_idx(0, ci, g);
    const unsigned short xbf = f2bf(X[(size_t)n*32 + ci]);
#pragma unroll
    for (int wi = 0; wi < 25; ++wi) hb[wi*544 + bw] = f2bf(h[wi] * rdeg);
    hb[25*544 + bw] = xbf;
    hb[26*544 + bw] = f2bf(hs * rdeg);
    hb[27*544 + bw] = xbf;
    __syncthreads();

    // ---- phase B ----
    const int lane = t & 63, w = t >> 6;
    const int m = lane & 15, qq = lane >> 4;
    const int co = (w & 3)*16 + m;
    if (w < 4) {
        f32x4 acc = {0.f, 0.f, 0.f, 0.f};
        for (int kk = 0; kk < 26; ++kk) {
            bf16x8 av = *(const bf16x8*)&hb[kk*544 + qq*136 + m*8];
            bf16x8 bv = *(const bf16x8*)(Wb1 + (size_t)((kk*4 + w)*64 + lane) * 8);
            acc = __builtin_amdgcn_mfma_f32_16x16x32_bf16(av, bv, acc, 0, 0, 0);
        }
        const float bb = b1[co];
#pragma unroll
        for (int r = 0; r < 4; ++r)
            agg1[(size_t)(n0 + qq*4 + r)*64 + co] = acc[r] + bb;
    } else {
        f32x4 accs = {0.f, 0.f, 0.f, 0.f};
#pragma unroll
        for (int s = 0; s < 2; ++s) {
            bf16x8 av = *(const bf16x8*)&hb[(26 + s)*544 + qq*136 + m*8];
            bf16x8 bv = *(const bf16x8*)(WbS + (size_t)((s*4 + (w & 3))*64 + lane) * 8);
            accs = __builtin_amdgcn_mfma_f32_16x16x32_bf16(av, bv, accs, 0, 0, 0);
        }
        const float bb = bs[co];
#pragma unroll
        for (int r = 0; r < 4; ++r)
            aggS[(size_t)(n0 + qq*4 + r)*64 + co] = accs[r] + bb;
    }
}

// ---------------- conv2: 16 nodes/block, node-paired packed edge loop ----------
// 512 threads, 8 waves. Wave w owns nodes 2w (.x) and 2w+1 (.y) in f32x2 lanes;
// lane = ci (0..63). Both edge lists walked in lockstep, 2 pairs in flight.
__global__ __launch_bounds__(512, 4) void k_conv2(
        const float* __restrict__ X,
        const int* __restrict__ off,
        const int4* __restrict__ ep,
        const unsigned short* __restrict__ Wb2,
        const float* __restrict__ b2,
        float* __restrict__ agg) {
    __shared__ __align__(16) unsigned short hb[52*544];  // 56.6 KB
    const int t = threadIdx.x, lane = t & 63, w = t >> 6;
    const int n0 = blockIdx.x * 16;
    const int kh = lane >> 5, r = lane & 31;   // k = wi*64 + lane -> kstep wi*2+kh

    const int nA = n0 + 2*w, nB = nA + 1;
    const int begA = off[nA], endA = off[nA + 1];
    const int begB = off[nB], endB = off[nB + 1];
    const int degA = endA - begA, degB = endB - begB;
    const int lastA = endA - 1, lastB = endB - 1;
    const float rdegA = 1.f / (float)max(degA, 1);
    const float rdegB = 1.f / (float)max(degB, 1);
    const int iters = max(degA, degB);

    f32x2 h2[25];
#pragma unroll
    for (int i = 0; i < 25; ++i) h2[i] = (f32x2){0.f, 0.f};

    for (int i = 0; i < iters; i += 2) {
        int4 pA[2], pB[2]; float xA[2], xB[2];
#pragma unroll
        for (int u = 0; u < 2; ++u) {
            pA[u] = ld_ep(ep, (unsigned)min(begA + i + u, lastA));
            pB[u] = ld_ep(ep, (unsigned)min(begB + i + u, lastB));
        }
#pragma unroll
        for (int u = 0; u < 2; ++u) {
            xA[u] = ld_x(X, (unsigned)pA[u].x * 256u + (unsigned)lane * 4u);
            xB[u] = ld_x(X, (unsigned)pB[u].x * 256u + (unsigned)lane * 4u);
            if (i + u >= degA) xA[u] = 0.f;
            if (i + u >= degB) xB[u] = 0.f;
        }
#pragma unroll
        for (int u = 0; u < 2; ++u) edge_acc_pair(h2, pA[u], pB[u], xA[u], xB[u]);
    }

    // ---- dump both nodes: wi -> ksteps wi*2+kh; x -> ksteps 50,51 ----
    const int bwA = us_idx(0, r, 2*w);
    const int bwB = us_idx(0, r, 2*w + 1);
#pragma unroll
    for (int wi = 0; wi < 25; ++wi) {
        hb[(wi*2 + kh)*544 + bwA] = f2bf(h2[wi].x * rdegA);
        hb[(wi*2 + kh)*544 + bwB] = f2bf(h2[wi].y * rdegB);
    }
    hb[(50 + kh)*544 + bwA] = f2bf(X[(size_t)nA*64 + lane]);
    hb[(50 + kh)*544 + bwB] = f2bf(X[(size_t)nB*64 + lane]);
    __syncthreads();

    if (w >= 4) return;

    const int m = lane & 15, qq = lane >> 4;
    f32x4 acc = {0.f, 0.f, 0.f, 0.f};
    for (int kk = 0; kk < 52; ++kk) {
        bf16x8 av = *(const bf16x8*)&hb[kk*544 + qq*136 + m*8];
        bf16x8 bv = *(const bf16x8*)(Wb2 + (size_t)((kk*4 + w)*64 + lane) * 8);
        acc = __builtin_amdgcn_mfma_f32_16x16x32_bf16(av, bv, acc, 0, 0, 0);
    }
    const int co = w*16 + m;
    const float bb = b2[co];
#pragma unroll
    for (int rr = 0; rr < 4; ++rr)
        agg[(size_t)(n0 + qq*4 + rr)*64 + co] = acc[rr] + bb;
}

// ---------------- batch norm ----------------
__global__ __launch_bounds__(256) void k_bnstats(const float* __restrict__ agg, float* stats) {
    __shared__ float sh0[256], sh1[256];
    int t = threadIdx.x;
    float s = 0.f, ss = 0.f;
    int stride = gridDim.x * 256;
    for (int i = blockIdx.x*256 + t; i < NN*64; i += stride) {
        float v = agg[i];
        s += v; ss += v*v;
    }
    sh0[t] = s; sh1[t] = ss;
    __syncthreads();
    if (t < 64) {
        float a = sh0[t] + sh0[t+64] + sh0[t+128] + sh0[t+192];
        float b = sh1[t] + sh1[t+64] + sh1[t+128] + sh1[t+192];
        atomicAdd(&stats[t], a);
        atomicAdd(&stats[64 + t], b);
    }
}

__device__ __forceinline__ float eluf(float u) { return u > 0.f ? u : expm1f(u); }

__global__ __launch_bounds__(256) void k_bn_elu(const float* __restrict__ agg,
                                                const float* __restrict__ stats,
                                                const float* __restrict__ gamma,
                                                const float* __restrict__ beta,
                                                float* __restrict__ out) {
    int i = blockIdx.x*256 + threadIdx.x;
    if (i >= NN*16) return;
    float4 v = ((const float4*)agg)[i];
    float r[4] = {v.x, v.y, v.z, v.w};
    int c0 = (i << 2) & 63;
#pragma unroll
    for (int j = 0; j < 4; j++) {
        int c = c0 + j;
        float mu = stats[c] * (1.f/NN);
        float var = stats[64 + c] * (1.f/NN) - mu*mu;
        float sc = gamma[c] * rsqrtf(fmaxf(var, 0.f) + 1e-5f);
        r[j] = eluf((r[j] - mu)*sc + beta[c]);
    }
    ((float4*)out)[i] = make_float4(r[0], r[1], r[2], r[3]);
}

__global__ __launch_bounds__(256) void k_bn_final(const float* __restrict__ a2,
                                                  const float* __restrict__ st2,
                                                  const float* __restrict__ g2,
                                                  const float* __restrict__ be2,
                                                  const float* __restrict__ as,
                                                  const float* __restrict__ sts,
                                                  const float* __restrict__ gs,
                                                  const float* __restrict__ bes,
                                                  float* __restrict__ out) {
    int i = blockIdx.x*256 + threadIdx.x;
    if (i >= NN*16) return;
    float4 v2 = ((const float4*)a2)[i];
    float4 vs = ((const float4*)as)[i];
    float r2v[4] = {v2.x, v2.y, v2.z, v2.w};
    float rsv[4] = {vs.x, vs.y, vs.z, vs.w};
    float o[4];
    int c0 = (i << 2) & 63;
#pragma unroll
    for (int j = 0; j < 4; j++) {
        int c = c0 + j;
        float mu2 = st2[c] * (1.f/NN);
        float var2 = st2[64 + c] * (1.f/NN) - mu2*mu2;
        float sc2 = g2[c] * rsqrtf(fmaxf(var2, 0.f) + 1e-5f);
        float mus = sts[c] * (1.f/NN);
        float vars = sts[64 + c] * (1.f/NN) - mus*mus;
        float scs = gs[c] * rsqrtf(fmaxf(vars, 0.f) + 1e-5f);
        float u = (r2v[j] - mu2)*sc2 + be2[c] + (rsv[j] - mus)*scs + bes[c];
        o[j] = eluf(u);
    }
    ((float4*)out)[i] = make_float4(o[0], o[1], o[2], o[3]);
}

extern "C" void kernel_launch(void* const* d_in, const int* in_sizes, int n_in,
                              void* d_out, int out_size, void* d_ws, size_t ws_size,
                              hipStream_t stream) {
    const float* x   = (const float*)d_in[0];
    const int*   ei  = (const int*)d_in[1];
    const float* ea  = (const float*)d_in[2];
    const float* w1  = (const float*)d_in[3];
    const float* r1  = (const float*)d_in[4];
    const float* b1  = (const float*)d_in[5];
    const float* g1  = (const float*)d_in[6];
    const float* be1 = (const float*)d_in[7];
    const float* w2  = (const float*)d_in[8];
    const float* r2  = (const float*)d_in[9];
    const float* b2  = (const float*)d_in[10];
    const float* g2  = (const float*)d_in[11];
    const float* be2 = (const float*)d_in[12];
    const float* wsN = (const float*)d_in[13];
    const float* rs  = (const float*)d_in[14];
    const float* bs  = (const float*)d_in[15];
    const float* gs  = (const float*)d_in[16];
    const float* bes = (const float*)d_in[17];
    const int* srcp = ei;
    const int* dstp = ei + NE;

    char* wsb = (char*)d_ws;
    size_t o = 0;
    auto alloc = [&](size_t bytes) -> char* {
        char* p = wsb + o;
        o += (bytes + 255) & ~(size_t)255;
        return p;
    };
    int*    degi    = (int*)   alloc((size_t)NN * 4);
    int*    cur     = (int*)   alloc((size_t)NN * 4);
    int*    off     = (int*)   alloc((size_t)(NN + 1) * 4);
    int*    bsum    = (int*)   alloc(256 * 4);
    int*    bpre    = (int*)   alloc(256 * 4);
    int4*   ep      = (int4*)  alloc((size_t)NE * 16);
    unsigned short* Wb1 = (unsigned short*)alloc(26 * 4096);
    unsigned short* WbS = (unsigned short*)alloc(2 * 4096);
    unsigned short* Wb2 = (unsigned short*)alloc(52 * 4096);
    float*  agg1    = (float*) alloc((size_t)NN * 64 * 4);  // reused for conv2 output
    float*  aggS    = (float*) alloc((size_t)NN * 64 * 4);
    float*  h1      = (float*) alloc((size_t)NN * 64 * 4);
    float*  stats   = (float*) alloc(384 * 4);
    (void)ws_size; (void)in_sizes; (void)n_in; (void)out_size;

    float* out = (float*)d_out;

    k_zero<<<196, 256, 0, stream>>>(degi, cur, stats);
    k_hist<<<3125, 256, 0, stream>>>(dstp, degi);
    k_scan_block<<<49, 256, 0, stream>>>(degi, off, bsum);
    k_scan_top<<<1, 256, 0, stream>>>(bsum, bpre, 49);
    k_scan_add<<<196, 256, 0, stream>>>(off, bpre);
    k_scatter<<<3125, 256, 0, stream>>>(srcp, dstp, ea, off, cur, ep);

    k_wprep<<<26, 256, 0, stream>>>(w1, r1, 800, Wb1);
    k_wprep<<<2, 256, 0, stream>>>(wsN, rs, 32, WbS);
    k_wprep<<<52, 256, 0, stream>>>(w2, r2, 1600, Wb2);

    k_conv1s<<<3125, 512, 0, stream>>>(x, off, ep, Wb1, WbS, b1, bs, agg1, aggS);
    k_bnstats<<<256, 256, 0, stream>>>(agg1, stats);
    k_bn_elu<<<3125, 256, 0, stream>>>(agg1, stats, g1, be1, h1);

    k_conv2<<<3125, 512, 0, stream>>>(h1, off, ep, Wb2, b2, agg1);
    k_bnstats<<<256, 256, 0, stream>>>(agg1, stats + 128);
    k_bnstats<<<256, 256, 0, stream>>>(aggS, stats + 256);
    k_bn_final<<<3125, 256, 0, stream>>>(agg1, stats + 128, g2, be2,
                                         aggS, stats + 256, gs, bes, out);
}

// Round 11
// 483.848 us; speedup vs baseline: 1.3824x; 1.0124x over previous
//
#include <hip/hip_runtime.h>

#define NN 50000
#define NE 800000
#define NEP (NE + 4*NN)   // padded edge capacity

typedef __attribute__((ext_vector_type(8))) short bf16x8;
typedef __attribute__((ext_vector_type(4))) float f32x4;
typedef __attribute__((ext_vector_type(2))) float f32x2;

__device__ __forceinline__ unsigned short f2bf(float f) {
    union { float f; unsigned u; } v; v.f = f;
    unsigned r = v.u + 0x7FFFu + ((v.u >> 16) & 1u);
    return (unsigned short)(r >> 16);
}

// byte-offset gathers (uniform 64-bit base + 32-bit voffset)
__device__ __forceinline__ int4 ld_ep(const int4* ep, unsigned byteoff) {
    return *(const int4*)((const char*)ep + (size_t)byteoff);
}
__device__ __forceinline__ float ld_x(const float* X, unsigned byteoff) {
    return *(const float*)((const char*)X + (size_t)byteoff);
}

// bf16 LDS A-fragment layout (16 nodes/block):
//   element (kstep kk, r = k&31, node m) at ushort index
//   kk*544 + (r>>3)*136 + m*8 + (r&7)
__device__ __forceinline__ int us_idx(int kk, int r, int m) {
    return kk*544 + (r >> 3)*136 + m*8 + (r & 7);
}

// dense hat-basis accumulate (one edge; v0,v1 raw): h[25] += x*wx*wy, hs += x.
template<bool HS>
__device__ __forceinline__ void edge_acc(float* h, float& hs, const int4& p, float x) {
    const f32x2 zero = {0.f, 0.f};
    f32x2 vp = {__int_as_float(p.z), __int_as_float(p.w)};
    f32x2 wxy[5];
#pragma unroll
    for (int r = 0; r < 5; ++r) {
        f32x2 wr = 1.f - __builtin_elementwise_abs(vp - (float)r);
        wxy[r] = __builtin_elementwise_max(wr, zero);
    }
    if (HS) hs += x;
#pragma unroll
    for (int r1 = 0; r1 < 5; ++r1) {
        float ty = x * wxy[r1].y;
#pragma unroll
        for (int r0 = 0; r0 < 5; ++r0)
            h[r1*5 + r0] = fmaf(wxy[r0].x, ty, h[r1*5 + r0]);
    }
}

// ---------------- setup kernels ----------------
__global__ __launch_bounds__(256) void k_zero(int* degi, int* cur, float* stats) {
    int i = blockIdx.x*256 + threadIdx.x;
    int stride = gridDim.x*256;
    for (int j = i; j < NN; j += stride) { degi[j] = 0; cur[j] = 0; }
    if (i < 384) stats[i] = 0.f;
}

__global__ __launch_bounds__(256) void k_hist(const int* __restrict__ dst, int* degi) {
    int e = blockIdx.x*256 + threadIdx.x;
    if (e < NE) atomicAdd(&degi[dst[e]], 1);
}

// exclusive scan over PADDED per-node counts ((deg+3)&~3)
__global__ __launch_bounds__(256) void k_scan_block(const int* __restrict__ degi,
                                                    int* off, int* bsum) {
    __shared__ int sh[256];
    int t = threadIdx.x;
    int base = blockIdx.x * 1024;
    int v[4]; int s = 0;
#pragma unroll
    for (int j = 0; j < 4; j++) {
        int idx = base + t*4 + j;
        v[j] = (idx < NN) ? ((degi[idx] + 3) & ~3) : 0;
        s += v[j];
    }
    sh[t] = s; __syncthreads();
    for (int ofs = 1; ofs < 256; ofs <<= 1) {
        int x = (t >= ofs) ? sh[t - ofs] : 0;
        __syncthreads();
        sh[t] += x;
        __syncthreads();
    }
    int ex = sh[t] - s;
#pragma unroll
    for (int j = 0; j < 4; j++) {
        int idx = base + t*4 + j;
        if (idx < NN) off[idx] = ex;
        ex += v[j];
    }
    if (t == 255) bsum[blockIdx.x] = sh[255];
}

__global__ __launch_bounds__(256) void k_scan_top(const int* __restrict__ bsum,
                                                  int* bpre, int nb) {
    __shared__ int sh[256];
    int t = threadIdx.x;
    int s = (t < nb) ? bsum[t] : 0;
    sh[t] = s; __syncthreads();
    for (int ofs = 1; ofs < 256; ofs <<= 1) {
        int x = (t >= ofs) ? sh[t - ofs] : 0;
        __syncthreads();
        sh[t] += x;
        __syncthreads();
    }
    if (t < nb) bpre[t] = sh[t] - s;
}

__global__ __launch_bounds__(256) void k_scan_add(int* off, const int* __restrict__ bpre) {
    int i = blockIdx.x*256 + threadIdx.x;
    if (i < NN) off[i] += bpre[i >> 10];
}

// ep = (src*256, src*128, v0, v1): pre-scaled byte offsets + raw spline coords.
__global__ __launch_bounds__(256) void k_scatter(const int* __restrict__ src,
                                                 const int* __restrict__ dst,
                                                 const float* __restrict__ ea,
                                                 const int* __restrict__ off, int* cur,
                                                 int4* __restrict__ ep) {
    int e = blockIdx.x*256 + threadIdx.x;
    if (e >= NE) return;
    int d = dst[e];
    int p = off[d] + atomicAdd(&cur[d], 1);
    float v0 = ea[2*e]     * 4.f;
    float v1 = ea[2*e + 1] * 4.f;
    int s = src[e];
    ep[p] = make_int4(s*256, s*128, __float_as_int(v0), __float_as_int(v1));
}

// fill pad slots with dummy edges pointing at the zero row (row NN), v=0.
__global__ __launch_bounds__(256) void k_padfill(const int* __restrict__ degi,
                                                 const int* __restrict__ off,
                                                 int4* __restrict__ ep) {
    int n = blockIdx.x*256 + threadIdx.x;
    if (n >= NN) return;
    int d = degi[n];
    int pd = (d + 3) & ~3;
    int4 dummy = make_int4(NN*256, NN*128, 0, 0);
    int base = off[n];
    for (int j = d; j < pd; ++j) ep[base + j] = dummy;
}

// copy x into ws with an extra zero row at index NN.
__global__ __launch_bounds__(256) void k_xz(const float4* __restrict__ x4, float4* xz4) {
    int i = blockIdx.x*256 + threadIdx.x;
    if (i < NN*8) xz4[i] = x4[i];
    else if (i < NN*8 + 8) xz4[i] = make_float4(0.f, 0.f, 0.f, 0.f);
}

// Pre-tile [W ; root] (f32, row-major [K,64]) into MFMA-B bf16 layout:
// Wb[((kk*4+cot)*64+lane)*8 + j] = src[k = kk*32+(lane>>4)*8+j][co = 16*cot+(lane&15)]
__global__ __launch_bounds__(256) void k_wprep(const float* __restrict__ W,
                                               const float* __restrict__ root,
                                               int KTC, unsigned short* Wb) {
    int tid = blockIdx.x*256 + threadIdx.x;
    int lane = tid & 63, cot = (tid >> 6) & 3, kk = tid >> 8;
    int co = 16*cot + (lane & 15);
    int kbase = kk*32 + ((lane >> 4) * 8);
    union { unsigned short s[8]; uint4 v; } u;
#pragma unroll
    for (int j = 0; j < 8; j++) {
        int k = kbase + j;
        float val = (k < KTC) ? W[(size_t)k*64 + co] : root[(size_t)(k - KTC)*64 + co];
        u.s[j] = f2bf(val);
    }
    *(uint4*)(Wb + (size_t)tid * 8) = u.v;
}

// ---------------- conv1 + convS fused: 16 nodes/block, bf16 LDS fragments ----
// 512 threads, 8 waves. Half-wave (t>>5) owns node g; ci = t&31.
// Phase B: waves 0-3 -> agg1 co-tile w (26 ksteps); waves 4-7 -> aggS (2 ksteps).
__global__ __launch_bounds__(512, 4) void k_conv1s(
        const float* __restrict__ XZ,          // (NN+1) x 32, row NN = 0
        const int* __restrict__ off,
        const int* __restrict__ degi,
        const int4* __restrict__ ep,
        const unsigned short* __restrict__ Wb1,
        const unsigned short* __restrict__ WbS,
        const float* __restrict__ b1,
        const float* __restrict__ bs,
        float* __restrict__ agg1,
        float* __restrict__ aggS) {
    __shared__ __align__(16) unsigned short hb[28*544];  // 30.5 KB
    const int t = threadIdx.x;
    const int g = t >> 5;          // node slot 0..15
    const int ci = t & 31;
    const unsigned ci4 = (unsigned)ci * 4u;
    const int n0 = blockIdx.x * 16;
    const int n = n0 + g;

    float h[25], hs = 0.f;
#pragma unroll
    for (int i = 0; i < 25; ++i) h[i] = 0.f;

    const int d = degi[n];
    const float rdeg = 1.f / (float)max(d, 1);
    unsigned b = (unsigned)off[n] * 16u;
    const unsigned bend = b + (unsigned)((d + 3) & ~3) * 16u;

    for (; b < bend; b += 64u) {
        int4 p[4]; float xv[4];
#pragma unroll
        for (int u = 0; u < 4; ++u) p[u] = ld_ep(ep, b + u*16u);
#pragma unroll
        for (int u = 0; u < 4; ++u) xv[u] = ld_x(XZ, (unsigned)p[u].y + ci4);
#pragma unroll
        for (int u = 0; u < 4; ++u) edge_acc<true>(h, hs, p[u], xv[u]);
    }

    // ---- dump bf16 fragments: kstep = wi; 25 = x; 26 = hs; 27 = x ----
    const int bw = us_idx(0, ci, g);
    const unsigned short xbf = f2bf(XZ[(size_t)n*32 + ci]);
#pragma unroll
    for (int wi = 0; wi < 25; ++wi) hb[wi*544 + bw] = f2bf(h[wi] * rdeg);
    hb[25*544 + bw] = xbf;
    hb[26*544 + bw] = f2bf(hs * rdeg);
    hb[27*544 + bw] = xbf;
    __syncthreads();

    // ---- phase B ----
    const int lane = t & 63, w = t >> 6;
    const int m = lane & 15, qq = lane >> 4;
    const int co = (w & 3)*16 + m;
    if (w < 4) {
        f32x4 acc = {0.f, 0.f, 0.f, 0.f};
        for (int kk = 0; kk < 26; ++kk) {
            bf16x8 av = *(const bf16x8*)&hb[kk*544 + qq*136 + m*8];
            bf16x8 bv = *(const bf16x8*)(Wb1 + (size_t)((kk*4 + w)*64 + lane) * 8);
            acc = __builtin_amdgcn_mfma_f32_16x16x32_bf16(av, bv, acc, 0, 0, 0);
        }
        const float bb = b1[co];
#pragma unroll
        for (int r = 0; r < 4; ++r)
            agg1[(size_t)(n0 + qq*4 + r)*64 + co] = acc[r] + bb;
    } else {
        f32x4 accs = {0.f, 0.f, 0.f, 0.f};
#pragma unroll
        for (int s = 0; s < 2; ++s) {
            bf16x8 av = *(const bf16x8*)&hb[(26 + s)*544 + qq*136 + m*8];
            bf16x8 bv = *(const bf16x8*)(WbS + (size_t)((s*4 + (w & 3))*64 + lane) * 8);
            accs = __builtin_amdgcn_mfma_f32_16x16x32_bf16(av, bv, accs, 0, 0, 0);
        }
        const float bb = bs[co];
#pragma unroll
        for (int r = 0; r < 4; ++r)
            aggS[(size_t)(n0 + qq*4 + r)*64 + co] = accs[r] + bb;
    }
}

// ---------------- conv2: 16 nodes/block, 2-chunk phase B (28.3 KB LDS) -------
// 512 threads, 8 waves. Wave w owns nodes 2w, 2w+1 sequentially; lane = ci 0..63.
// Chunk 0: wi 0..12 (global ksteps 0..25); chunk 1: wi 13..24 + x (26..51).
__global__ __launch_bounds__(512, 4) void k_conv2(
        const float* __restrict__ XZ,          // (NN+1) x 64, row NN = 0
        const int* __restrict__ off,
        const int* __restrict__ degi,
        const int4* __restrict__ ep,
        const unsigned short* __restrict__ Wb2,
        const float* __restrict__ b2,
        float* __restrict__ agg) {
    __shared__ __align__(16) unsigned short hb[26*544];  // 28.3 KB
    const int t = threadIdx.x, lane = t & 63, w = t >> 6;
    const int n0 = blockIdx.x * 16;
    const int kh = lane >> 5, r = lane & 31;   // k = wi*64 + lane -> kstep wi*2+kh
    const unsigned l4 = (unsigned)lane * 4u;

    float h[2][25];
    float rdg[2];
#pragma unroll
    for (int nn = 0; nn < 2; ++nn) {
        const int n = n0 + 2*w + nn;
#pragma unroll
        for (int i = 0; i < 25; ++i) h[nn][i] = 0.f;
        float hsd = 0.f;
        const int d = degi[n];
        rdg[nn] = 1.f / (float)max(d, 1);
        unsigned b = (unsigned)off[n] * 16u;
        const unsigned bend = b + (unsigned)((d + 3) & ~3) * 16u;
        for (; b < bend; b += 64u) {
            int4 p[4]; float xv[4];
#pragma unroll
            for (int u = 0; u < 4; ++u) p[u] = ld_ep(ep, b + u*16u);
#pragma unroll
            for (int u = 0; u < 4; ++u) xv[u] = ld_x(XZ, (unsigned)p[u].x + l4);
#pragma unroll
            for (int u = 0; u < 4; ++u) edge_acc<false>(h[nn], hsd, p[u], xv[u]);
        }
    }

    const int m = lane & 15, qq = lane >> 4;
    const int bwA = us_idx(0, r, 2*w), bwB = us_idx(0, r, 2*w + 1);
    f32x4 acc = {0.f, 0.f, 0.f, 0.f};

    // ---- chunk 0: wi 0..12 -> local ksteps wi*2+kh (0..25) = global 0..25 ----
#pragma unroll
    for (int wi = 0; wi < 13; ++wi) {
        hb[(wi*2 + kh)*544 + bwA] = f2bf(h[0][wi] * rdg[0]);
        hb[(wi*2 + kh)*544 + bwB] = f2bf(h[1][wi] * rdg[1]);
    }
    __syncthreads();
    if (w < 4) {
        for (int kk = 0; kk < 26; ++kk) {
            bf16x8 av = *(const bf16x8*)&hb[kk*544 + qq*136 + m*8];
            bf16x8 bv = *(const bf16x8*)(Wb2 + (size_t)((kk*4 + w)*64 + lane) * 8);
            acc = __builtin_amdgcn_mfma_f32_16x16x32_bf16(av, bv, acc, 0, 0, 0);
        }
    }
    __syncthreads();   // MFMA reads done before chunk-1 overwrite

    // ---- chunk 1: wi 13..24 -> local (wi-13)*2+kh (0..23); x -> 24,25 ----
#pragma unroll
    for (int wi = 13; wi < 25; ++wi) {
        hb[((wi - 13)*2 + kh)*544 + bwA] = f2bf(h[0][wi] * rdg[0]);
        hb[((wi - 13)*2 + kh)*544 + bwB] = f2bf(h[1][wi] * rdg[1]);
    }
    hb[(24 + kh)*544 + bwA] = f2bf(XZ[(size_t)(n0 + 2*w)*64 + lane]);
    hb[(24 + kh)*544 + bwB] = f2bf(XZ[(size_t)(n0 + 2*w + 1)*64 + lane]);
    __syncthreads();

    if (w >= 4) return;
    for (int kk = 0; kk < 26; ++kk) {
        bf16x8 av = *(const bf16x8*)&hb[kk*544 + qq*136 + m*8];
        bf16x8 bv = *(const bf16x8*)(Wb2 + (size_t)(((26 + kk)*4 + w)*64 + lane) * 8);
        acc = __builtin_amdgcn_mfma_f32_16x16x32_bf16(av, bv, acc, 0, 0, 0);
    }
    const int co = w*16 + m;
    const float bb = b2[co];
#pragma unroll
    for (int rr = 0; rr < 4; ++rr)
        agg[(size_t)(n0 + qq*4 + rr)*64 + co] = acc[rr] + bb;
}

// ---------------- batch norm ----------------
__global__ __launch_bounds__(256) void k_bnstats(const float* __restrict__ agg, float* stats) {
    __shared__ float sh0[256], sh1[256];
    int t = threadIdx.x;
    float s = 0.f, ss = 0.f;
    int stride = gridDim.x * 256;
    for (int i = blockIdx.x*256 + t; i < NN*64; i += stride) {
        float v = agg[i];
        s += v; ss += v*v;
    }
    sh0[t] = s; sh1[t] = ss;
    __syncthreads();
    if (t < 64) {
        float a = sh0[t] + sh0[t+64] + sh0[t+128] + sh0[t+192];
        float b = sh1[t] + sh1[t+64] + sh1[t+128] + sh1[t+192];
        atomicAdd(&stats[t], a);
        atomicAdd(&stats[64 + t], b);
    }
}

__device__ __forceinline__ float eluf(float u) { return u > 0.f ? u : expm1f(u); }

// writes out rows 0..NN-1; also zeroes row NN (out must have NN+1 rows).
__global__ __launch_bounds__(256) void k_bn_elu(const float* __restrict__ agg,
                                                const float* __restrict__ stats,
                                                const float* __restrict__ gamma,
                                                const float* __restrict__ beta,
                                                float* __restrict__ out) {
    int i = blockIdx.x*256 + threadIdx.x;
    if (i >= NN*16) {
        if (i < NN*16 + 16) ((float4*)out)[i] = make_float4(0.f, 0.f, 0.f, 0.f);
        return;
    }
    float4 v = ((const float4*)agg)[i];
    float r[4] = {v.x, v.y, v.z, v.w};
    int c0 = (i << 2) & 63;
#pragma unroll
    for (int j = 0; j < 4; j++) {
        int c = c0 + j;
        float mu = stats[c] * (1.f/NN);
        float var = stats[64 + c] * (1.f/NN) - mu*mu;
        float sc = gamma[c] * rsqrtf(fmaxf(var, 0.f) + 1e-5f);
        r[j] = eluf((r[j] - mu)*sc + beta[c]);
    }
    ((float4*)out)[i] = make_float4(r[0], r[1], r[2], r[3]);
}

__global__ __launch_bounds__(256) void k_bn_final(const float* __restrict__ a2,
                                                  const float* __restrict__ st2,
                                                  const float* __restrict__ g2,
                                                  const float* __restrict__ be2,
                                                  const float* __restrict__ as,
                                                  const float* __restrict__ sts,
                                                  const float* __restrict__ gs,
                                                  const float* __restrict__ bes,
                                                  float* __restrict__ out) {
    int i = blockIdx.x*256 + threadIdx.x;
    if (i >= NN*16) return;
    float4 v2 = ((const float4*)a2)[i];
    float4 vs = ((const float4*)as)[i];
    float r2v[4] = {v2.x, v2.y, v2.z, v2.w};
    float rsv[4] = {vs.x, vs.y, vs.z, vs.w};
    float o[4];
    int c0 = (i << 2) & 63;
#pragma unroll
    for (int j = 0; j < 4; j++) {
        int c = c0 + j;
        float mu2 = st2[c] * (1.f/NN);
        float var2 = st2[64 + c] * (1.f/NN) - mu2*mu2;
        float sc2 = g2[c] * rsqrtf(fmaxf(var2, 0.f) + 1e-5f);
        float mus = sts[c] * (1.f/NN);
        float vars = sts[64 + c] * (1.f/NN) - mus*mus;
        float scs = gs[c] * rsqrtf(fmaxf(vars, 0.f) + 1e-5f);
        float u = (r2v[j] - mu2)*sc2 + be2[c] + (rsv[j] - mus)*scs + bes[c];
        o[j] = eluf(u);
    }
    ((float4*)out)[i] = make_float4(o[0], o[1], o[2], o[3]);
}

extern "C" void kernel_launch(void* const* d_in, const int* in_sizes, int n_in,
                              void* d_out, int out_size, void* d_ws, size_t ws_size,
                              hipStream_t stream) {
    const float* x   = (const float*)d_in[0];
    const int*   ei  = (const int*)d_in[1];
    const float* ea  = (const float*)d_in[2];
    const float* w1  = (const float*)d_in[3];
    const float* r1  = (const float*)d_in[4];
    const float* b1  = (const float*)d_in[5];
    const float* g1  = (const float*)d_in[6];
    const float* be1 = (const float*)d_in[7];
    const float* w2  = (const float*)d_in[8];
    const float* r2  = (const float*)d_in[9];
    const float* b2  = (const float*)d_in[10];
    const float* g2  = (const float*)d_in[11];
    const float* be2 = (const float*)d_in[12];
    const float* wsN = (const float*)d_in[13];
    const float* rs  = (const float*)d_in[14];
    const float* bs  = (const float*)d_in[15];
    const float* gs  = (const float*)d_in[16];
    const float* bes = (const float*)d_in[17];
    const int* srcp = ei;
    const int* dstp = ei + NE;

    char* wsb = (char*)d_ws;
    size_t o = 0;
    auto alloc = [&](size_t bytes) -> char* {
        char* p = wsb + o;
        o += (bytes + 255) & ~(size_t)255;
        return p;
    };
    int*    degi    = (int*)   alloc((size_t)NN * 4);
    int*    cur     = (int*)   alloc((size_t)NN * 4);
    int*    off     = (int*)   alloc((size_t)(NN + 1) * 4);
    int*    bsum    = (int*)   alloc(256 * 4);
    int*    bpre    = (int*)   alloc(256 * 4);
    int4*   ep      = (int4*)  alloc((size_t)NEP * 16);
    unsigned short* Wb1 = (unsigned short*)alloc(26 * 4096);
    unsigned short* WbS = (unsigned short*)alloc(2 * 4096);
    unsigned short* Wb2 = (unsigned short*)alloc(52 * 4096);
    float*  xz      = (float*) alloc((size_t)(NN + 1) * 32 * 4);
    float*  agg1    = (float*) alloc((size_t)NN * 64 * 4);  // reused for conv2 output
    float*  aggS    = (float*) alloc((size_t)NN * 64 * 4);
    float*  h1      = (float*) alloc((size_t)(NN + 1) * 64 * 4);  // +zero row
    float*  stats   = (float*) alloc(384 * 4);
    (void)ws_size; (void)in_sizes; (void)n_in; (void)out_size;

    float* out = (float*)d_out;

    k_zero<<<196, 256, 0, stream>>>(degi, cur, stats);
    k_hist<<<3125, 256, 0, stream>>>(dstp, degi);
    k_scan_block<<<49, 256, 0, stream>>>(degi, off, bsum);
    k_scan_top<<<1, 256, 0, stream>>>(bsum, bpre, 49);
    k_scan_add<<<196, 256, 0, stream>>>(off, bpre);
    k_scatter<<<3125, 256, 0, stream>>>(srcp, dstp, ea, off, cur, ep);
    k_padfill<<<196, 256, 0, stream>>>(degi, off, ep);
    k_xz<<<1564, 256, 0, stream>>>((const float4*)x, (float4*)xz);

    k_wprep<<<26, 256, 0, stream>>>(w1, r1, 800, Wb1);
    k_wprep<<<2, 256, 0, stream>>>(wsN, rs, 32, WbS);
    k_wprep<<<52, 256, 0, stream>>>(w2, r2, 1600, Wb2);

    k_conv1s<<<3125, 512, 0, stream>>>(xz, off, degi, ep, Wb1, WbS, b1, bs, agg1, aggS);
    k_bnstats<<<256, 256, 0, stream>>>(agg1, stats);
    k_bn_elu<<<3126, 256, 0, stream>>>(agg1, stats, g1, be1, h1);

    k_conv2<<<3125, 512, 0, stream>>>(h1, off, degi, ep, Wb2, b2, agg1);
    k_bnstats<<<256, 256, 0, stream>>>(agg1, stats + 128);
    k_bnstats<<<256, 256, 0, stream>>>(aggS, stats + 256);
    k_bn_final<<<3125, 256, 0, stream>>>(agg1, stats + 128, g2, be2,
                                         aggS, stats + 256, gs, bes, out);
}